// Round 4
// baseline (198.986 us; speedup 1.0000x reference)
//
#include <hip/hip_runtime.h>

#define WEIGHT 0.1f
#define THRESH 0.3f
#define MARGIN 0.1f

#define NTHREADS 256
#define ROWS_PER_THREAD 32
#define ROWS_PER_BLOCK (NTHREADS * ROWS_PER_THREAD)   // 8192

// Native clang vector type: __builtin_nontemporal_load requires a real
// vector-of-float, not HIP's struct float4.
typedef float vfloat4 __attribute__((ext_vector_type(4)));

// d_ws layout: [0 .. nblocks) doubles = per-block totals, then nblocks uints.
// Every launch writes ALL slots (grid fixed by n), so 0xAA poison is harmless.
//
// KEY (R6/R7): the harness poison-fills 512 MiB of d_ws before every timed
// launch (2 x ~78us fill kernels INSIDE the timed region — a fixed ~157us
// floor), leaving L2/L3 full of dirty lines and the input evicted to HBM.
// Allocating reads then force a 64B writeback per 64B read — halving
// effective read BW (the ~2.6 TB/s plateau of R2-R5). Non-temporal loads
// skip allocation => pure HBM read stream. Zero reuse => NT is also the
// semantically right policy.
//
// R8 POST-MORTEM (do NOT re-attempt): fusing finalize into the main kernel
// via last-block-done (threadfence + agent-scope ACQ_REL atomic) regressed
// 35us -> 391us. Mechanisms: (1) tail code flipped codegen to VGPR=24,
// serializing the in-flight loads; (2) agent-scope release on multi-XCD
// gfx950 emits buffer_wbl2/buffer_inv PER BLOCK, serializing at L2. The
// finalize launch (~5-8us) is cheaper than any in-kernel device handoff.
//
// R10: RPT 8 -> 16: 201.0 -> 196.9us. Main kernel was latency/overhead-
// limited, not BW-saturated. R11: RPT 16 -> 32 (64 in-flight NT loads/
// thread, 1024 blocks, ~175 VGPR, no spill). Same axis, one more step.

__device__ __forceinline__ void row_terms(vfloat4 p, float t,
                                          float& acc, unsigned int& cnt) {
    // p[1]=p4, p[2]=p5, p[3]=p6 (p[0] unused)
    bool g4 = p.y > THRESH;
    bool g5 = p.z > THRESH;
    bool g6 = p.w > THRESH;
    bool m45  = g4 && g5;
    bool m56  = g5 && g6;
    bool m456 = m45 && g6;

    float term45 = fmaxf(MARGIN - (p.z * t - p.y * t), 0.0f);
    float term56 = fmaxf(MARGIN - (p.w * t - p.z * t), 0.0f);
    float d45 = fabsf(p.z - p.y);
    float d56 = fabsf(p.w - p.z);
    float torder = fmaxf(d45 - d56 + MARGIN, 0.0f);

    acc += (m45  ? term45 : 0.0f)
         + (m56  ? term56 : 0.0f)
         + (m456 ? torder : 0.0f);
    cnt += (unsigned)m45 + (unsigned)m56 + (unsigned)m456;
}

__global__ __launch_bounds__(NTHREADS) void tc_main_kernel(
        const vfloat4* __restrict__ pred,
        const float*   __restrict__ times,
        double*        __restrict__ blk_tot,
        unsigned int*  __restrict__ blk_cnt,
        int n) {
    float local = 0.0f;
    unsigned int cnt = 0;

    const int  tid       = threadIdx.x;
    const long blockBase = (long)blockIdx.x * ROWS_PER_BLOCK;

    if (blockBase + ROWS_PER_BLOCK <= (long)n) {
        // 64 independent, per-instruction-coalesced, NON-TEMPORAL loads
        // issued before any use.
        vfloat4 p[ROWS_PER_THREAD];
        float   t[ROWS_PER_THREAD];
#pragma unroll
        for (int r = 0; r < ROWS_PER_THREAD; ++r)
            p[r] = __builtin_nontemporal_load(&pred[blockBase + (long)r * NTHREADS + tid]);
#pragma unroll
        for (int r = 0; r < ROWS_PER_THREAD; ++r)
            t[r] = __builtin_nontemporal_load(&times[blockBase + (long)r * NTHREADS + tid]);
#pragma unroll
        for (int r = 0; r < ROWS_PER_THREAD; ++r)
            row_terms(p[r], t[r], local, cnt);
    } else {
        for (long i = blockBase + tid; i < (long)n; i += NTHREADS) {
            vfloat4 p = __builtin_nontemporal_load(&pred[i]);
            float   t = __builtin_nontemporal_load(&times[i]);
            row_terms(p, t, local, cnt);
        }
    }

    // Wave-64 butterfly reduction (promote total to double for the tree)
    double dl = (double)local;
    for (int o = 32; o > 0; o >>= 1) {
        dl  += __shfl_down(dl, o, 64);
        cnt += __shfl_down(cnt, o, 64);
    }

    __shared__ double       s_tot[NTHREADS / 64];
    __shared__ unsigned int s_cnt[NTHREADS / 64];
    int wave = threadIdx.x >> 6;
    int lane = threadIdx.x & 63;
    if (lane == 0) { s_tot[wave] = dl; s_cnt[wave] = cnt; }
    __syncthreads();

    if (threadIdx.x == 0) {
        double bt = 0.0;
        unsigned int bc = 0;
        for (int w = 0; w < NTHREADS / 64; ++w) { bt += s_tot[w]; bc += s_cnt[w]; }
        blk_tot[blockIdx.x] = bt;     // distinct slot per block: no contention
        blk_cnt[blockIdx.x] = bc;
    }
}

__global__ __launch_bounds__(NTHREADS) void tc_finalize_kernel(
        const double*       __restrict__ blk_tot,
        const unsigned int* __restrict__ blk_cnt,
        float* __restrict__ out,
        int nblocks) {
    double dl = 0.0;
    unsigned long long cl = 0;
    for (int i = threadIdx.x; i < nblocks; i += NTHREADS) {
        dl += blk_tot[i];
        cl += blk_cnt[i];
    }
    for (int o = 32; o > 0; o >>= 1) {
        dl += __shfl_down(dl, o, 64);
        cl += __shfl_down(cl, o, 64);
    }
    __shared__ double             s_tot[NTHREADS / 64];
    __shared__ unsigned long long s_cnt[NTHREADS / 64];
    int wave = threadIdx.x >> 6;
    int lane = threadIdx.x & 63;
    if (lane == 0) { s_tot[wave] = dl; s_cnt[wave] = cl; }
    __syncthreads();
    if (threadIdx.x == 0) {
        double total = 0.0;
        unsigned long long count = 0;
        for (int w = 0; w < NTHREADS / 64; ++w) { total += s_tot[w]; count += s_cnt[w]; }
        double c = (double)count;
        double loss = (count > 0) ? (total / fmax(c, 1.0)) : total;
        out[0] = (float)((double)WEIGHT * loss);
    }
}

extern "C" void kernel_launch(void* const* d_in, const int* in_sizes, int n_in,
                              void* d_out, int out_size, void* d_ws, size_t ws_size,
                              hipStream_t stream) {
    const vfloat4* pred  = (const vfloat4*)d_in[0];  // (B,4) fp32 -> one vfloat4/row
    const float*   times = (const float*)d_in[1];    // (B,1) fp32
    int n = in_sizes[1];                             // B = rows

    int nblocks = (n + ROWS_PER_BLOCK - 1) / ROWS_PER_BLOCK;   // 1024 for B=2^23

    double*       blk_tot = (double*)d_ws;
    unsigned int* blk_cnt = (unsigned int*)((char*)d_ws + (size_t)nblocks * sizeof(double));

    tc_main_kernel<<<nblocks, NTHREADS, 0, stream>>>(pred, times, blk_tot, blk_cnt, n);
    tc_finalize_kernel<<<1, NTHREADS, 0, stream>>>(blk_tot, blk_cnt, (float*)d_out, nblocks);
}

// Round 5
// 196.366 us; speedup vs baseline: 1.0133x; 1.0133x over previous
//
#include <hip/hip_runtime.h>

#define WEIGHT 0.1f
#define THRESH 0.3f
#define MARGIN 0.1f

#define NTHREADS 256
#define ROWS_PER_THREAD 16
#define ROWS_PER_BLOCK (NTHREADS * ROWS_PER_THREAD)   // 4096

// Native clang vector type: __builtin_nontemporal_load requires a real
// vector-of-float, not HIP's struct float4.
typedef float vfloat4 __attribute__((ext_vector_type(4)));

// d_ws layout: [0 .. nblocks) doubles = per-block totals, then nblocks uints.
// Every launch writes ALL slots (grid fixed by n), so 0xAA poison is harmless.
//
// KEY (R6/R7): the harness poison-fills 512 MiB of d_ws before every timed
// launch (2 x ~78us fill kernels INSIDE the timed region — a fixed ~157us
// floor), leaving L2/L3 full of dirty lines and the input evicted to HBM.
// Allocating reads then force a 64B writeback per 64B read — halving
// effective read BW (the ~2.6 TB/s plateau of R2-R5). Non-temporal loads
// skip allocation => pure HBM read stream. Zero reuse => NT is also the
// semantically right policy.
//
// R8 POST-MORTEM (do NOT re-attempt): fusing finalize into the main kernel
// via last-block-done (threadfence + agent-scope ACQ_REL atomic) regressed
// 35us -> 391us. Mechanisms: (1) tail code flipped codegen to VGPR=24,
// serializing the in-flight loads; (2) agent-scope release on multi-XCD
// gfx950 emits buffer_wbl2/buffer_inv PER BLOCK, serializing at L2. The
// finalize launch (~5-8us) is cheaper than any in-kernel device handoff.
//
// TUNING LADDER (harness-verified):
//   RPT=8  : 199.3-201.0 us
//   RPT=16 : 196.9 us   <- sweet spot (~96 VGPR, ~5 waves/SIMD, 2048 blocks)
//   RPT=32 : 199.0 us   (VGPR ~175 -> occupancy drop outweighs extra MLP)
// Remaining gap to the 187us arithmetic floor (157 fills + 24.5 read + 6
// finalize) is launch ramp + tail drain — probed unschedulable (R8, R11).

__device__ __forceinline__ void row_terms(vfloat4 p, float t,
                                          float& acc, unsigned int& cnt) {
    // p[1]=p4, p[2]=p5, p[3]=p6 (p[0] unused)
    bool g4 = p.y > THRESH;
    bool g5 = p.z > THRESH;
    bool g6 = p.w > THRESH;
    bool m45  = g4 && g5;
    bool m56  = g5 && g6;
    bool m456 = m45 && g6;

    float term45 = fmaxf(MARGIN - (p.z * t - p.y * t), 0.0f);
    float term56 = fmaxf(MARGIN - (p.w * t - p.z * t), 0.0f);
    float d45 = fabsf(p.z - p.y);
    float d56 = fabsf(p.w - p.z);
    float torder = fmaxf(d45 - d56 + MARGIN, 0.0f);

    acc += (m45  ? term45 : 0.0f)
         + (m56  ? term56 : 0.0f)
         + (m456 ? torder : 0.0f);
    cnt += (unsigned)m45 + (unsigned)m56 + (unsigned)m456;
}

__global__ __launch_bounds__(NTHREADS) void tc_main_kernel(
        const vfloat4* __restrict__ pred,
        const float*   __restrict__ times,
        double*        __restrict__ blk_tot,
        unsigned int*  __restrict__ blk_cnt,
        int n) {
    float local = 0.0f;
    unsigned int cnt = 0;

    const int  tid       = threadIdx.x;
    const long blockBase = (long)blockIdx.x * ROWS_PER_BLOCK;

    if (blockBase + ROWS_PER_BLOCK <= (long)n) {
        // 32 independent, per-instruction-coalesced, NON-TEMPORAL loads
        // issued before any use.
        vfloat4 p[ROWS_PER_THREAD];
        float   t[ROWS_PER_THREAD];
#pragma unroll
        for (int r = 0; r < ROWS_PER_THREAD; ++r)
            p[r] = __builtin_nontemporal_load(&pred[blockBase + (long)r * NTHREADS + tid]);
#pragma unroll
        for (int r = 0; r < ROWS_PER_THREAD; ++r)
            t[r] = __builtin_nontemporal_load(&times[blockBase + (long)r * NTHREADS + tid]);
#pragma unroll
        for (int r = 0; r < ROWS_PER_THREAD; ++r)
            row_terms(p[r], t[r], local, cnt);
    } else {
        for (long i = blockBase + tid; i < (long)n; i += NTHREADS) {
            vfloat4 p = __builtin_nontemporal_load(&pred[i]);
            float   t = __builtin_nontemporal_load(&times[i]);
            row_terms(p, t, local, cnt);
        }
    }

    // Wave-64 butterfly reduction (promote total to double for the tree)
    double dl = (double)local;
    for (int o = 32; o > 0; o >>= 1) {
        dl  += __shfl_down(dl, o, 64);
        cnt += __shfl_down(cnt, o, 64);
    }

    __shared__ double       s_tot[NTHREADS / 64];
    __shared__ unsigned int s_cnt[NTHREADS / 64];
    int wave = threadIdx.x >> 6;
    int lane = threadIdx.x & 63;
    if (lane == 0) { s_tot[wave] = dl; s_cnt[wave] = cnt; }
    __syncthreads();

    if (threadIdx.x == 0) {
        double bt = 0.0;
        unsigned int bc = 0;
        for (int w = 0; w < NTHREADS / 64; ++w) { bt += s_tot[w]; bc += s_cnt[w]; }
        blk_tot[blockIdx.x] = bt;     // distinct slot per block: no contention
        blk_cnt[blockIdx.x] = bc;
    }
}

__global__ __launch_bounds__(NTHREADS) void tc_finalize_kernel(
        const double*       __restrict__ blk_tot,
        const unsigned int* __restrict__ blk_cnt,
        float* __restrict__ out,
        int nblocks) {
    double dl = 0.0;
    unsigned long long cl = 0;
    for (int i = threadIdx.x; i < nblocks; i += NTHREADS) {
        dl += blk_tot[i];
        cl += blk_cnt[i];
    }
    for (int o = 32; o > 0; o >>= 1) {
        dl += __shfl_down(dl, o, 64);
        cl += __shfl_down(cl, o, 64);
    }
    __shared__ double             s_tot[NTHREADS / 64];
    __shared__ unsigned long long s_cnt[NTHREADS / 64];
    int wave = threadIdx.x >> 6;
    int lane = threadIdx.x & 63;
    if (lane == 0) { s_tot[wave] = dl; s_cnt[wave] = cl; }
    __syncthreads();
    if (threadIdx.x == 0) {
        double total = 0.0;
        unsigned long long count = 0;
        for (int w = 0; w < NTHREADS / 64; ++w) { total += s_tot[w]; count += s_cnt[w]; }
        double c = (double)count;
        double loss = (count > 0) ? (total / fmax(c, 1.0)) : total;
        out[0] = (float)((double)WEIGHT * loss);
    }
}

extern "C" void kernel_launch(void* const* d_in, const int* in_sizes, int n_in,
                              void* d_out, int out_size, void* d_ws, size_t ws_size,
                              hipStream_t stream) {
    const vfloat4* pred  = (const vfloat4*)d_in[0];  // (B,4) fp32 -> one vfloat4/row
    const float*   times = (const float*)d_in[1];    // (B,1) fp32
    int n = in_sizes[1];                             // B = rows

    int nblocks = (n + ROWS_PER_BLOCK - 1) / ROWS_PER_BLOCK;   // 2048 for B=2^23

    double*       blk_tot = (double*)d_ws;
    unsigned int* blk_cnt = (unsigned int*)((char*)d_ws + (size_t)nblocks * sizeof(double));

    tc_main_kernel<<<nblocks, NTHREADS, 0, stream>>>(pred, times, blk_tot, blk_cnt, n);
    tc_finalize_kernel<<<1, NTHREADS, 0, stream>>>(blk_tot, blk_cnt, (float*)d_out, nblocks);
}